// Round 3
// baseline (225.595 us; speedup 1.0000x reference)
//
#include <hip/hip_runtime.h>

#define NT     25600   // B*S tokens
#define WCH    16      // chars per token
#define DIM    64
#define VOCAB  96
#define HID    128
#define OC     400     // conv output features
#define TCOLS  1400    // T table columns: sum over windows of w*100
#define CPITCH 416     // padded w_proj K pitch (multiple of 32)
#define TOKB   32      // tokens per block in fused kernel
#define CLP    424     // convL LDS pitch (halves): 16B-aligned rows
#define XLP    136     // xbf LDS pitch (halves): 16B-aligned rows

typedef __attribute__((ext_vector_type(8))) _Float16 h8;
typedef __attribute__((ext_vector_type(4))) float f32x4;
typedef __attribute__((ext_vector_type(2))) _Float16 f16x2;

// ---------------- K1: T[c][tcol] (f16), tcol = TB[wi] + j*100 + f ----------------
// T[c, wi, j, f] = sum_d cv[c,d] * filt_wi[f, j*64+d]
__global__ void k_table(const float* __restrict__ cv,
                        const float* __restrict__ f2,
                        const float* __restrict__ f3,
                        const float* __restrict__ f4,
                        const float* __restrict__ f5,
                        _Float16* __restrict__ T) {
  int idx = blockIdx.x * 256 + threadIdx.x;
  if (idx >= VOCAB * TCOLS) return;
  int c = idx / TCOLS, tcol = idx - c * TCOLS;
  int wi, tb;
  if (tcol < 200)      { wi = 0; tb = 0; }
  else if (tcol < 500) { wi = 1; tb = 200; }
  else if (tcol < 900) { wi = 2; tb = 500; }
  else                 { wi = 3; tb = 900; }
  int r = tcol - tb, j = r / 100, f = r - j * 100;
  const float* filt = (wi == 0) ? f2 : (wi == 1) ? f3 : (wi == 2) ? f4 : f5;
  const float* frow = filt + (size_t)f * ((wi + 2) * DIM) + j * DIM;
  const float* crow = cv + c * DIM;
  float s = 0.f;
#pragma unroll 8
  for (int d = 0; d < DIM; ++d) s += crow[d] * frow[d];
  T[idx] = (_Float16)s;
}

// ---------------- K2: weight prep (fp32 -> f16) ----------------
// [0, 53248): wprojP[128][416] zero-padded; then 4x 128*128 highway weights.
__global__ void k_prep(const float* __restrict__ wproj,
                       const float* __restrict__ tw0, const float* __restrict__ gw0,
                       const float* __restrict__ tw1, const float* __restrict__ gw1,
                       _Float16* __restrict__ wprojP,
                       _Float16* __restrict__ hw) {  // hw = tw0h|gw0h|tw1h|gw1h
  int idx = blockIdx.x * 256 + threadIdx.x;
  if (idx < HID * CPITCH) {
    int n = idx / CPITCH, k = idx - n * CPITCH;
    wprojP[idx] = (k < OC) ? (_Float16)wproj[n * OC + k] : (_Float16)0.f;
    return;
  }
  int j = idx - HID * CPITCH;
  if (j >= 4 * HID * HID) return;
  int which = j >> 14, r = j & 16383;
  const float* src = (which == 0) ? tw0 : (which == 1) ? gw0 : (which == 2) ? tw1 : gw1;
  hw[j] = (_Float16)src[r];
}

// conv pair for window WI at even feature f: max over positions of (s, s').
// chp entries are pre-multiplied by TCOLS.
template<int WI>
__device__ __forceinline__ float2 conv_pair(const _Float16* __restrict__ T,
                                            const int* __restrict__ chp, int f) {
  constexpr int W = WI + 2;
  constexpr int L = 15 - WI;
  constexpr int TB = (WI == 0) ? 0 : (WI == 1) ? 200 : (WI == 2) ? 500 : 900;
  float m0 = -1e30f, m1 = -1e30f;
#pragma unroll
  for (int l = 0; l < L; ++l) {
    float s0 = 0.f, s1 = 0.f;
#pragma unroll
    for (int j = 0; j < W; ++j) {
      f16x2 v = *(const f16x2*)(T + chp[l + j] + TB + j * 100 + f);
      s0 += (float)v.x;
      s1 += (float)v.y;
    }
    m0 = fmaxf(m0, s0);
    m1 = fmaxf(m1, s1);
  }
  return make_float2(m0, m1);
}

__device__ __forceinline__ float tanh_fast(float m) {
  m = fminf(fmaxf(m, -15.f), 15.f);
  float e = __expf(2.f * m);
  return (e - 1.f) / (e + 1.f);
}

// ---------------- K3: fused conv-lookup + MFMA proj + 2 highway layers ----------------
// 32 tokens/block, 256 threads (4 waves). Each wave covers n-tiles {wave, wave+4}.
// A-frag (16x16x32 f16): A[m=lane&15][k=quad*8+j]; D: row=quad*4+reg, col=lane&15.
__global__ __launch_bounds__(256) void k_fused(
    const int* __restrict__ chars,
    const _Float16* __restrict__ T,
    const _Float16* __restrict__ wprojP,
    const _Float16* __restrict__ hw,    // tw0h|gw0h|tw1h|gw1h, 128*128 each
    const float* __restrict__ tb0, const float* __restrict__ tb1,
    const float* __restrict__ gb0, const float* __restrict__ gb1,
    float* __restrict__ out) {
  __shared__ __align__(16) _Float16 convL[TOKB * CLP];  // 27,136 B
  __shared__ __align__(16) _Float16 xbf[TOKB * XLP];    //  8,704 B
  __shared__ __align__(16) int chS[TOKB * WCH];         //  2,048 B

  const int tid = threadIdx.x;
  const int wave = tid >> 6, lane = tid & 63;
  const int m16 = lane & 15, quad = lane >> 4;
  const int tok0 = blockIdx.x * TOKB;
  const f32x4 zero = {0.f, 0.f, 0.f, 0.f};

  // ---- stage chars (pre-multiplied by TCOLS) ----
  chS[tid]       = chars[tok0 * WCH + tid] * TCOLS;
  chS[tid + 256] = chars[tok0 * WCH + tid + 256] * TCOLS;
  __syncthreads();

  // ---- phase 1: conv via T-lookups, tanh(max) fusion, f16x2-paired loads ----
  for (int p = tid; p < TOKB * 200; p += 256) {     // 25 iterations
    int token = p / 200;
    int o = (p - token * 200) * 2;                  // even feature 0..398
    const int* chp = chS + token * WCH;
    float2 m;
    if (o < 100)      m = conv_pair<0>(T, chp, o);
    else if (o < 200) m = conv_pair<1>(T, chp, o - 100);
    else if (o < 300) m = conv_pair<2>(T, chp, o - 200);
    else              m = conv_pair<3>(T, chp, o - 300);
    convL[token * CLP + o]     = (_Float16)tanh_fast(m.x);
    convL[token * CLP + o + 1] = (_Float16)tanh_fast(m.y);
  }
  // zero pad cols 400..415
  for (int z = tid; z < TOKB * 16; z += 256)
    convL[(z >> 4) * CLP + 400 + (z & 15)] = (_Float16)0.f;
  __syncthreads();

  // ---- phase 2: projection GEMM xp = conv @ wproj^T (K=416 incl. zero pad) ----
  const int hcA = wave * 16 + m16;        // n-tile wave
  const int hcB = hcA + 64;               // n-tile wave+4
  f32x4 xp[2][2];
#pragma unroll
  for (int mt = 0; mt < 2; ++mt)
#pragma unroll
    for (int nt = 0; nt < 2; ++nt) xp[mt][nt] = zero;

  for (int kstep = 0; kstep < 13; ++kstep) {
    const int ko = kstep * 32 + quad * 8;
    h8 b0 = *(const h8*)(wprojP + (size_t)hcA * CPITCH + ko);
    h8 b1 = *(const h8*)(wprojP + (size_t)hcB * CPITCH + ko);
    h8 a0 = *(const h8*)(convL + m16 * CLP + ko);
    h8 a1 = *(const h8*)(convL + (16 + m16) * CLP + ko);
    xp[0][0] = __builtin_amdgcn_mfma_f32_16x16x32_f16(a0, b0, xp[0][0], 0, 0, 0);
    xp[0][1] = __builtin_amdgcn_mfma_f32_16x16x32_f16(a0, b1, xp[0][1], 0, 0, 0);
    xp[1][0] = __builtin_amdgcn_mfma_f32_16x16x32_f16(a1, b0, xp[1][0], 0, 0, 0);
    xp[1][1] = __builtin_amdgcn_mfma_f32_16x16x32_f16(a1, b1, xp[1][1], 0, 0, 0);
  }

  // write x0 as f16 for layer-0 A-frags
#pragma unroll
  for (int mt = 0; mt < 2; ++mt)
#pragma unroll
    for (int nt = 0; nt < 2; ++nt)
#pragma unroll
      for (int r = 0; r < 4; ++r)
        xbf[(mt * 16 + quad * 4 + r) * XLP + nt * 64 + hcA] = (_Float16)xp[mt][nt][r];
  __syncthreads();

  // ---- highway layers ----
#pragma unroll
  for (int layer = 0; layer < 2; ++layer) {
    const _Float16* tw = hw + (layer ? 2 : 0) * HID * HID;
    const _Float16* gw = hw + (layer ? 3 : 1) * HID * HID;
    const float* tbv = layer ? tb1 : tb0;
    const float* gbv = layer ? gb1 : gb0;
    float btA = tbv[hcA], bgA = gbv[hcA];
    float btB = tbv[hcB], bgB = gbv[hcB];

    f32x4 at[2][2], ag[2][2];
#pragma unroll
    for (int mt = 0; mt < 2; ++mt)
#pragma unroll
      for (int nt = 0; nt < 2; ++nt) { at[mt][nt] = zero; ag[mt][nt] = zero; }

#pragma unroll
    for (int kstep = 0; kstep < 4; ++kstep) {
      const int ko = kstep * 32 + quad * 8;
      h8 bt0 = *(const h8*)(tw + (size_t)hcA * HID + ko);
      h8 bt1 = *(const h8*)(tw + (size_t)hcB * HID + ko);
      h8 bg0 = *(const h8*)(gw + (size_t)hcA * HID + ko);
      h8 bg1 = *(const h8*)(gw + (size_t)hcB * HID + ko);
#pragma unroll
      for (int mt = 0; mt < 2; ++mt) {
        h8 a = *(const h8*)(xbf + (mt * 16 + m16) * XLP + ko);
        at[mt][0] = __builtin_amdgcn_mfma_f32_16x16x32_f16(a, bt0, at[mt][0], 0, 0, 0);
        at[mt][1] = __builtin_amdgcn_mfma_f32_16x16x32_f16(a, bt1, at[mt][1], 0, 0, 0);
        ag[mt][0] = __builtin_amdgcn_mfma_f32_16x16x32_f16(a, bg0, ag[mt][0], 0, 0, 0);
        ag[mt][1] = __builtin_amdgcn_mfma_f32_16x16x32_f16(a, bg1, ag[mt][1], 0, 0, 0);
      }
    }
    __syncthreads();   // xbf reads done before overwrite / exit

#pragma unroll
    for (int mt = 0; mt < 2; ++mt)
#pragma unroll
      for (int nt = 0; nt < 2; ++nt) {
        float bt = nt ? btB : btA, bg = nt ? bgB : bgA;
#pragma unroll
        for (int r = 0; r < 4; ++r) {
          float g = 1.f / (1.f + __expf(-(ag[mt][nt][r] + bg)));
          float tt = fmaxf(at[mt][nt][r] + bt, 0.f);
          float xn = g * tt + (1.f - g) * xp[mt][nt][r];  // residual fp32 in regs
          xp[mt][nt][r] = xn;
          int row = mt * 16 + quad * 4 + r;
          int col = nt * 64 + hcA;
          if (layer == 0) {
            xbf[row * XLP + col] = (_Float16)xn;
          } else {
            out[(size_t)(tok0 + row) * HID + col] = xn;
          }
        }
      }
    if (layer == 0) __syncthreads();
  }
}

extern "C" void kernel_launch(void* const* d_in, const int* in_sizes, int n_in,
                              void* d_out, int out_size, void* d_ws, size_t ws_size,
                              hipStream_t stream) {
  (void)in_sizes; (void)n_in; (void)out_size; (void)ws_size;
  const int* chars   = (const int*)d_in[0];
  const float* cv    = (const float*)d_in[1];
  const float* f2    = (const float*)d_in[2];
  const float* f3    = (const float*)d_in[3];
  const float* f4    = (const float*)d_in[4];
  const float* f5    = (const float*)d_in[5];
  const float* wpj   = (const float*)d_in[6];
  const float* tw0   = (const float*)d_in[7];
  const float* tb0   = (const float*)d_in[8];
  const float* tw1   = (const float*)d_in[9];
  const float* tb1   = (const float*)d_in[10];
  const float* gw0   = (const float*)d_in[11];
  const float* gb0   = (const float*)d_in[12];
  const float* gw1   = (const float*)d_in[13];
  const float* gb1   = (const float*)d_in[14];
  float* out = (float*)d_out;

  char* ws = (char*)d_ws;
  _Float16* T      = (_Float16*)ws;                   // 268,800 B
  _Float16* wprojP = (_Float16*)(ws + 268800);        // 106,496 B
  _Float16* hw     = (_Float16*)(ws + 268800 + 106496); // 131,072 B (total 506,368 B)

  k_table<<<(VOCAB * TCOLS + 255) / 256, 256, 0, stream>>>(cv, f2, f3, f4, f5, T);
  k_prep<<<(HID * CPITCH + 4 * HID * HID + 255) / 256, 256, 0, stream>>>(
      wpj, tw0, gw0, tw1, gw1, wprojP, hw);
  k_fused<<<NT / TOKB, 256, 0, stream>>>(chars, T, wprojP, hw,
                                         tb0, tb1, gb0, gb1, out);
}

// Round 4
// 182.545 us; speedup vs baseline: 1.2358x; 1.2358x over previous
//
#include <hip/hip_runtime.h>

#define NT     25600   // B*S tokens
#define WCH    16      // chars per token
#define DIM    64
#define VOCAB  96
#define HID    128
#define FPAD   104     // per-window feature pitch (100 real + 4 zero pad)
#define NSLOT  14      // total j-slots: 2+3+4+5
#define TROW   (NSLOT * FPAD)   // 1456 elements per char row in T
#define KP     416     // GEMM K = 4*FPAD (matches padded w_proj)
#define TOKB   16      // tokens per block in fused kernel
#define CLP    424     // convL LDS pitch (halves)
#define XLP    136     // xbf LDS pitch (halves)

typedef __attribute__((ext_vector_type(8))) _Float16 h8;
typedef __attribute__((ext_vector_type(4))) float f32x4;

__device__ __forceinline__ h8 hmax8(h8 a, h8 b) {
  h8 r;
#pragma unroll
  for (int i = 0; i < 8; ++i) r[i] = a[i] > b[i] ? a[i] : b[i];
  return r;
}

__device__ __forceinline__ float tanh_fast(float m) {
  m = fminf(fmaxf(m, -15.f), 15.f);
  float e = __expf(2.f * m);
  return (e - 1.f) / (e + 1.f);
}

// ================= prep kernel: 3 roles by blockIdx =================
// A [0,42):   T[c][slot][104] f16 via LDS-staged filter slice (slot = b/3, cgroup = b%3)
// B [42,106): wprojP[128][416] f16, k = wi*104+f mapping, pad->0
// C [106,362): hw = tw0|gw0|tw1|gw1 as f16, 128*128 each
__global__ __launch_bounds__(256) void k_prep(
    const float* __restrict__ cv,
    const float* __restrict__ f2, const float* __restrict__ f3,
    const float* __restrict__ f4, const float* __restrict__ f5,
    const float* __restrict__ wproj,
    const float* __restrict__ tw0, const float* __restrict__ gw0,
    const float* __restrict__ tw1, const float* __restrict__ gw1,
    _Float16* __restrict__ T, _Float16* __restrict__ wprojP,
    _Float16* __restrict__ hw) {
  __shared__ float fS[100 * 65];   // filter slice [f][d], pitch 65
  __shared__ float cvS[32 * 65];   // char-vector slice [c][d], pitch 65
  const int tid = threadIdx.x;
  const int b = blockIdx.x;

  if (b < 42) {
    const int slot = b / 3, cg = b % 3;
    int wi, j;
    if (slot < 2)      { wi = 0; j = slot; }
    else if (slot < 5) { wi = 1; j = slot - 2; }
    else if (slot < 9) { wi = 2; j = slot - 5; }
    else               { wi = 3; j = slot - 9; }
    const float* filt = (wi == 0) ? f2 : (wi == 1) ? f3 : (wi == 2) ? f4 : f5;
    const int rowlen = (wi + 2) * DIM;
    for (int idx = tid; idx < 100 * DIM; idx += 256) {
      int f = idx >> 6, d = idx & 63;
      fS[f * 65 + d] = filt[f * rowlen + j * DIM + d];
    }
    for (int idx = tid; idx < 32 * DIM; idx += 256) {
      int c = idx >> 6, d = idx & 63;
      cvS[c * 65 + d] = cv[(cg * 32 + c) * DIM + d];
    }
    __syncthreads();
    for (int o = tid; o < 32 * FPAD; o += 256) {
      int cl = o & 31, fo = o >> 5;
      float s = 0.f;
      if (fo < 100) {
#pragma unroll 8
        for (int d = 0; d < DIM; ++d) s += cvS[cl * 65 + d] * fS[fo * 65 + d];
      }
      T[(size_t)(cg * 32 + cl) * TROW + slot * FPAD + fo] = (_Float16)s;
    }
  } else if (b < 106) {
    const int bb = b - 42;
    const int n = bb * 2 + (tid >> 7);
    const int k0 = tid & 127;
    for (int k = k0; k < KP; k += 128) {
      int wi = (k < 104) ? 0 : (k < 208) ? 1 : (k < 312) ? 2 : 3;
      int f = k - wi * FPAD;
      wprojP[n * KP + k] =
          (f < 100) ? (_Float16)wproj[n * 400 + wi * 100 + f] : (_Float16)0.f;
    }
  } else {
    const int idx = (b - 106) * 256 + tid;   // < 65536
    const int which = idx >> 14, r = idx & 16383;
    const float* src = (which == 0) ? tw0 : (which == 1) ? gw0
                     : (which == 2) ? tw1 : gw1;
    hw[idx] = (_Float16)src[r];
  }
}

// ================= fused conv-lookup + MFMA head =================
// chS entries premultiplied by TROW. Threads tid<208: item = token*13 + octet.
template<int WI>
__device__ __forceinline__ void conv_win(const _Float16* __restrict__ T,
                                         const int* __restrict__ chS,
                                         _Float16* __restrict__ convL, int tid) {
  if (tid >= TOKB * 13) return;
  constexpr int W = WI + 2, L = 15 - WI;
  constexpr int SB = (WI == 0) ? 0 : (WI == 1) ? 2 : (WI == 2) ? 5 : 9;
  const int token = (tid * 1262) >> 14;        // tid/13, exact for tid<208
  const int octet = tid - token * 13;
  const int* chp = chS + token * WCH;
  const _Float16* Tb = T + SB * FPAD + octet * 8;
  h8 m;
  {
    h8 s = *(const h8*)(Tb + chp[0]);
#pragma unroll
    for (int j = 1; j < W; ++j) s += *(const h8*)(Tb + chp[j] + j * FPAD);
    m = s;
  }
#pragma unroll
  for (int l = 1; l < L; ++l) {
    h8 s = *(const h8*)(Tb + chp[l]);
#pragma unroll
    for (int j = 1; j < W; ++j) s += *(const h8*)(Tb + chp[l + j] + j * FPAD);
    m = hmax8(m, s);
  }
  h8 r;
#pragma unroll
  for (int i = 0; i < 8; ++i) r[i] = (_Float16)tanh_fast((float)m[i]);
  *(h8*)(convL + token * CLP + WI * FPAD + octet * 8) = r;
}

// 16 tokens/block, 256 threads (4 waves). Wave w covers hid cols {w*16.., +64..}.
// A-frag (16x16x32 f16): A[m=lane&15][k=quad*8+j]; D: row=quad*4+reg, col=lane&15.
__global__ __launch_bounds__(256) void k_fused(
    const int* __restrict__ chars,
    const _Float16* __restrict__ T,
    const _Float16* __restrict__ wprojP,
    const _Float16* __restrict__ hw,
    const float* __restrict__ tb0, const float* __restrict__ tb1,
    const float* __restrict__ gb0, const float* __restrict__ gb1,
    float* __restrict__ out) {
  __shared__ __align__(16) _Float16 convL[TOKB * CLP];  // 13,568 B
  __shared__ __align__(16) _Float16 xbf[TOKB * XLP];    //  4,352 B
  __shared__ __align__(16) int chS[TOKB * WCH];         //  1,024 B

  const int tid = threadIdx.x;
  const int wave = tid >> 6, lane = tid & 63;
  const int m16 = lane & 15, quad = lane >> 4;
  const int tok0 = blockIdx.x * TOKB;
  const f32x4 zero = {0.f, 0.f, 0.f, 0.f};

  chS[tid] = chars[tok0 * WCH + tid] * TROW;
  __syncthreads();

  conv_win<0>(T, chS, convL, tid);
  conv_win<1>(T, chS, convL, tid);
  conv_win<2>(T, chS, convL, tid);
  conv_win<3>(T, chS, convL, tid);
  __syncthreads();

  // ---- projection GEMM: xp = conv @ wprojP^T, K=416 ----
  const int hcA = wave * 16 + m16;
  const int hcB = hcA + 64;
  f32x4 xpA = zero, xpB = zero;
  for (int kstep = 0; kstep < 13; ++kstep) {
    const int ko = kstep * 32 + quad * 8;
    h8 a  = *(const h8*)(convL + m16 * CLP + ko);
    h8 b0 = *(const h8*)(wprojP + (size_t)hcA * KP + ko);
    h8 b1 = *(const h8*)(wprojP + (size_t)hcB * KP + ko);
    xpA = __builtin_amdgcn_mfma_f32_16x16x32_f16(a, b0, xpA, 0, 0, 0);
    xpB = __builtin_amdgcn_mfma_f32_16x16x32_f16(a, b1, xpB, 0, 0, 0);
  }

#pragma unroll
  for (int r = 0; r < 4; ++r) {
    xbf[(quad * 4 + r) * XLP + hcA]      = (_Float16)xpA[r];
    xbf[(quad * 4 + r) * XLP + 64 + hcA] = (_Float16)xpB[r];
  }
  __syncthreads();

  // ---- highway layers ----
#pragma unroll
  for (int layer = 0; layer < 2; ++layer) {
    const _Float16* tw = hw + (layer ? 2 : 0) * HID * HID;
    const _Float16* gw = hw + (layer ? 3 : 1) * HID * HID;
    const float* tbv = layer ? tb1 : tb0;
    const float* gbv = layer ? gb1 : gb0;
    float btA = tbv[hcA], bgA = gbv[hcA];
    float btB = tbv[hcB], bgB = gbv[hcB];

    f32x4 atA = zero, atB = zero, agA = zero, agB = zero;
#pragma unroll
    for (int kstep = 0; kstep < 4; ++kstep) {
      const int ko = kstep * 32 + quad * 8;
      h8 a   = *(const h8*)(xbf + m16 * XLP + ko);
      h8 bt0 = *(const h8*)(tw + (size_t)hcA * HID + ko);
      h8 bt1 = *(const h8*)(tw + (size_t)hcB * HID + ko);
      h8 bg0 = *(const h8*)(gw + (size_t)hcA * HID + ko);
      h8 bg1 = *(const h8*)(gw + (size_t)hcB * HID + ko);
      atA = __builtin_amdgcn_mfma_f32_16x16x32_f16(a, bt0, atA, 0, 0, 0);
      atB = __builtin_amdgcn_mfma_f32_16x16x32_f16(a, bt1, atB, 0, 0, 0);
      agA = __builtin_amdgcn_mfma_f32_16x16x32_f16(a, bg0, agA, 0, 0, 0);
      agB = __builtin_amdgcn_mfma_f32_16x16x32_f16(a, bg1, agB, 0, 0, 0);
    }
    __syncthreads();   // xbf reads done before overwrite

#pragma unroll
    for (int r = 0; r < 4; ++r) {
      float gA = 1.f / (1.f + __expf(-(agA[r] + bgA)));
      float gB = 1.f / (1.f + __expf(-(agB[r] + bgB)));
      float tA = fmaxf(atA[r] + btA, 0.f);
      float tB = fmaxf(atB[r] + btB, 0.f);
      float xA = gA * tA + (1.f - gA) * xpA[r];
      float xB = gB * tB + (1.f - gB) * xpB[r];
      xpA[r] = xA; xpB[r] = xB;
      int row = quad * 4 + r;
      if (layer == 0) {
        xbf[row * XLP + hcA]      = (_Float16)xA;
        xbf[row * XLP + 64 + hcA] = (_Float16)xB;
      } else {
        out[(size_t)(tok0 + row) * HID + hcA]      = xA;
        out[(size_t)(tok0 + row) * HID + 64 + hcA] = xB;
      }
    }
    if (layer == 0) __syncthreads();
  }
}

extern "C" void kernel_launch(void* const* d_in, const int* in_sizes, int n_in,
                              void* d_out, int out_size, void* d_ws, size_t ws_size,
                              hipStream_t stream) {
  (void)in_sizes; (void)n_in; (void)out_size; (void)ws_size;
  const int* chars = (const int*)d_in[0];
  const float* cv  = (const float*)d_in[1];
  const float* f2  = (const float*)d_in[2];
  const float* f3  = (const float*)d_in[3];
  const float* f4  = (const float*)d_in[4];
  const float* f5  = (const float*)d_in[5];
  const float* wpj = (const float*)d_in[6];
  const float* tw0 = (const float*)d_in[7];
  const float* tb0 = (const float*)d_in[8];
  const float* tw1 = (const float*)d_in[9];
  const float* tb1 = (const float*)d_in[10];
  const float* gw0 = (const float*)d_in[11];
  const float* gb0 = (const float*)d_in[12];
  const float* gw1 = (const float*)d_in[13];
  const float* gb1 = (const float*)d_in[14];
  float* out = (float*)d_out;

  char* ws = (char*)d_ws;
  _Float16* T      = (_Float16*)ws;                       // 96*1456*2 = 279,552 B
  _Float16* wprojP = (_Float16*)(ws + 279552);            // 106,496 B
  _Float16* hw     = (_Float16*)(ws + 279552 + 106496);   // 131,072 B (total 517,120 B)

  k_prep<<<362, 256, 0, stream>>>(cv, f2, f3, f4, f5, wpj, tw0, gw0, tw1, gw1,
                                  T, wprojP, hw);
  k_fused<<<NT / TOKB, 256, 0, stream>>>(chars, T, wprojP, hw,
                                         tb0, tb1, gb0, gb1, out);
}